// Round 1
// baseline (400.989 us; speedup 1.0000x reference)
//
#include <hip/hip_runtime.h>
#include <math.h>

#define H 128
#define TOPK 5
#define INV_TEMP 5.0f

// ---------------- degree count ----------------
__global__ __launch_bounds__(256) void deg_kernel(
    const int* __restrict__ src, const int* __restrict__ dst,
    int* __restrict__ in_deg, int* __restrict__ out_deg, int E)
{
  int e = blockIdx.x * 256 + threadIdx.x;
  if (e < E) {
    atomicAdd(&in_deg[dst[e]], 1);
    atomicAdd(&out_deg[src[e]], 1);
  }
}

// ---------------- exclusive scan of in_deg -> offs[0..N] ----------------
__global__ __launch_bounds__(1024) void scan_kernel(
    const int* __restrict__ deg, int* __restrict__ offs, int n)
{
  __shared__ int sums[1024];
  int tid = threadIdx.x;
  int per = (n + 1023) >> 10;
  int start = tid * per;
  int end = min(start + per, n);
  int s = 0;
  for (int i = start; i < end; ++i) s += deg[i];
  sums[tid] = s;
  __syncthreads();
  for (int off = 1; off < 1024; off <<= 1) {
    int v = (tid >= off) ? sums[tid - off] : 0;
    __syncthreads();
    sums[tid] += v;
    __syncthreads();
  }
  int run = (tid == 0) ? 0 : sums[tid - 1];
  for (int i = start; i < end; ++i) { offs[i] = run; run += deg[i]; }
  if (tid == 1023) offs[n] = sums[1023];
}

// ---------------- bucket fill (payload = rel | inv<<16) ----------------
__global__ __launch_bounds__(256) void fill_kernel(
    const int* __restrict__ dst, const int* __restrict__ rel, const int* __restrict__ inv,
    const int* __restrict__ offs, int* __restrict__ cursor, int* __restrict__ bucket, int E)
{
  int e = blockIdx.x * 256 + threadIdx.x;
  if (e < E) {
    int d = dst[e];
    int pos = offs[d] + atomicAdd(&cursor[d], 1);
    bucket[pos] = rel[e] | (inv[e] << 16);
  }
}

// ---------------- zero-total-degree node list ----------------
__global__ __launch_bounds__(256) void zerolist_kernel(
    const int* __restrict__ in_deg, const int* __restrict__ out_deg,
    int* __restrict__ zlist, int* __restrict__ zcount, int N)
{
  int n = blockIdx.x * 256 + threadIdx.x;
  if (n < N && (in_deg[n] + out_deg[n]) == 0) {
    int p = atomicAdd(zcount, 1);
    zlist[p] = n;
  }
}

// ---------------- l2-normalize res_ent_emb rows -> z2 ----------------
__global__ __launch_bounds__(64) void norm_res_kernel(
    const float* __restrict__ res, float* __restrict__ z2)
{
  int r = blockIdx.x;
  int lane = threadIdx.x;
  float x0 = res[(size_t)r * H + lane];
  float x1 = res[(size_t)r * H + lane + 64];
  float ss = x0 * x0 + x1 * x1;
  #pragma unroll
  for (int off = 32; off > 0; off >>= 1) ss += __shfl_xor(ss, off, 64);
  float iv = 1.0f / fmaxf(sqrtf(ss), 1e-12f);
  z2[(size_t)r * H + lane] = x0 * iv;
  z2[(size_t)r * H + lane + 64] = x1 * iv;
}

// ---------------- per-node mean gather (one wave per node) ----------------
__global__ __launch_bounds__(256) void gather_kernel(
    const int* __restrict__ offs, const int* __restrict__ bucket,
    const float* __restrict__ rhead, const float* __restrict__ rtail,
    float* __restrict__ feat, int N)
{
  int gid = blockIdx.x * 256 + threadIdx.x;
  int wid = gid >> 6;
  int lane = gid & 63;
  if (wid >= N) return;
  int b = offs[wid], e2 = offs[wid + 1];
  float a0 = 0.f, a1 = 0.f;
  for (int p = b; p < e2; ++p) {
    int pay = bucket[p];
    int r = pay & 0xFFFF;
    const float* row = ((pay >> 16) ? rhead : rtail) + (size_t)r * H;
    a0 += row[lane];
    a1 += row[lane + 64];
  }
  int deg = e2 - b;
  float sc = 1.0f / (float)(deg > 0 ? deg : 1);
  feat[(size_t)wid * H + lane] = a0 * sc;
  feat[(size_t)wid * H + lane + 64] = a1 * sc;
}

// ---------------- zero-node fallback: topk-softmax retrieval ----------------
// 4 zero-nodes per block; sims shared in LDS; per-wave top-5 selection.
__global__ __launch_bounds__(256) void zero_emb_kernel(
    const int* __restrict__ zlist, const int* __restrict__ zcount,
    const float* __restrict__ ent, const float* __restrict__ z2,
    const float* __restrict__ res_raw, float* __restrict__ feat, int NRES_)
{
  __shared__ __align__(16) float z1s[4][H];
  __shared__ float sims[4][2048];
  int t = threadIdx.x;
  int w = t >> 6;
  int lane = t & 63;
  int Z = *zcount;
  int ngroups = (Z + 3) >> 2;
  for (int g = blockIdx.x; g < ngroups; g += gridDim.x) {
    int zi0 = g * 4;
    int nv = min(4, Z - zi0);
    // normalize node row (wave w handles node w)
    if (w < nv) {
      int n = zlist[zi0 + w];
      float x0 = ent[(size_t)n * H + lane];
      float x1 = ent[(size_t)n * H + lane + 64];
      float ss = x0 * x0 + x1 * x1;
      #pragma unroll
      for (int off = 32; off > 0; off >>= 1) ss += __shfl_xor(ss, off, 64);
      float iv = 1.0f / fmaxf(sqrtf(ss), 1e-12f);
      z1s[w][lane] = x0 * iv;
      z1s[w][lane + 64] = x1 * iv;
    } else {
      z1s[w][lane] = 0.f;
      z1s[w][lane + 64] = 0.f;
    }
    __syncthreads();
    // sims for 4 nodes sharing each z2-row read
    for (int j = t; j < NRES_; j += 256) {
      const float4* zr = (const float4*)(z2 + (size_t)j * H);
      float s0 = 0.f, s1 = 0.f, s2 = 0.f, s3 = 0.f;
      #pragma unroll
      for (int q = 0; q < 32; ++q) {
        float4 v = zr[q];
        float4 a0 = *(const float4*)&z1s[0][4 * q];
        float4 a1 = *(const float4*)&z1s[1][4 * q];
        float4 a2 = *(const float4*)&z1s[2][4 * q];
        float4 a3 = *(const float4*)&z1s[3][4 * q];
        s0 += v.x * a0.x + v.y * a0.y + v.z * a0.z + v.w * a0.w;
        s1 += v.x * a1.x + v.y * a1.y + v.z * a1.z + v.w * a1.w;
        s2 += v.x * a2.x + v.y * a2.y + v.z * a2.z + v.w * a2.w;
        s3 += v.x * a3.x + v.y * a3.y + v.z * a3.z + v.w * a3.w;
      }
      sims[0][j] = s0; sims[1][j] = s1; sims[2][j] = s2; sims[3][j] = s3;
    }
    __syncthreads();
    // per-wave top-5 + softmax + weighted sum
    if (w < nv) {
      int n = zlist[zi0 + w];
      float tv[TOPK]; int ti[TOPK];
      #pragma unroll
      for (int k = 0; k < TOPK; ++k) { tv[k] = -1e30f; ti[k] = 0x7fffffff; }
      for (int j = lane; j < NRES_; j += 64) {
        float s = sims[w][j];
        if (s > tv[TOPK - 1] || (s == tv[TOPK - 1] && j < ti[TOPK - 1])) {
          tv[TOPK - 1] = s; ti[TOPK - 1] = j;
          #pragma unroll
          for (int k = TOPK - 1; k > 0; --k) {
            if (tv[k] > tv[k - 1] || (tv[k] == tv[k - 1] && ti[k] < ti[k - 1])) {
              float a = tv[k]; tv[k] = tv[k - 1]; tv[k - 1] = a;
              int bI = ti[k]; ti[k] = ti[k - 1]; ti[k - 1] = bI;
            }
          }
        }
      }
      int head = 0;
      float topv[TOPK]; int topi[TOPK];
      for (int r = 0; r < TOPK; ++r) {
        float bv = (head < TOPK) ? tv[head] : -1e30f;
        int bi = (head < TOPK) ? ti[head] : 0x7fffffff;
        #pragma unroll
        for (int off = 32; off > 0; off >>= 1) {
          float ov = __shfl_xor(bv, off, 64);
          int oi = __shfl_xor(bi, off, 64);
          if (ov > bv || (ov == bv && oi < bi)) { bv = ov; bi = oi; }
        }
        topv[r] = bv; topi[r] = bi;
        if (head < TOPK && ti[head] == bi) head++;
      }
      float m = topv[0];
      float wk[TOPK]; float wsum = 0.f;
      #pragma unroll
      for (int k = 0; k < TOPK; ++k) { wk[k] = expf((topv[k] - m) * INV_TEMP); wsum += wk[k]; }
      float inv_ws = 1.0f / wsum;
      float a0 = 0.f, a1 = 0.f;
      #pragma unroll
      for (int k = 0; k < TOPK; ++k) {
        const float* rr = res_raw + (size_t)topi[k] * H;
        a0 += wk[k] * rr[lane];
        a1 += wk[k] * rr[lane + 64];
      }
      feat[(size_t)n * H + lane] = a0 * inv_ws;
      feat[(size_t)n * H + lane + 64] = a1 * inv_ws;
    }
    __syncthreads();
  }
}

// ---------------- fused 2-layer MLP ----------------
// block = 256 threads, 32 rows; feat rows staged in LDS; W streamed from L2.
#define ROWS 32
#define RPT 16
__global__ __launch_bounds__(256) void mlp_kernel(
    const float* __restrict__ feat,
    const float* __restrict__ W1, const float* __restrict__ b1,
    const float* __restrict__ W2, const float* __restrict__ b2,
    float* __restrict__ out, int N)
{
  __shared__ __align__(16) float frow[ROWS][132];
  __shared__ __align__(16) float hrow[ROWS][132];
  int t = threadIdx.x;
  int row0 = blockIdx.x * ROWS;
  // stage feat rows (float4), zero-pad OOB rows
  for (int k = t; k < ROWS * 32; k += 256) {
    int r = k >> 5, q = k & 31;
    float4 v = make_float4(0.f, 0.f, 0.f, 0.f);
    if (row0 + r < N) v = *(const float4*)(feat + (size_t)(row0 + r) * H + 4 * q);
    *(float4*)&frow[r][4 * q] = v;
  }
  __syncthreads();
  int i = t & 127;     // output index
  int rg = t >> 7;     // row group (0/1)
  float acc[RPT];
  // ---- layer 1 ----
  {
    float bias = b1[i];
    #pragma unroll
    for (int k = 0; k < RPT; ++k) acc[k] = bias;
    const float4* wv4 = (const float4*)(W1 + (size_t)i * H);
    for (int q = 0; q < 32; ++q) {
      float4 wv = wv4[q];
      #pragma unroll
      for (int k = 0; k < RPT; ++k) {
        float4 fv = *(const float4*)&frow[rg * RPT + k][4 * q];
        acc[k] += wv.x * fv.x + wv.y * fv.y + wv.z * fv.z + wv.w * fv.w;
      }
    }
    #pragma unroll
    for (int k = 0; k < RPT; ++k) hrow[rg * RPT + k][i] = fmaxf(acc[k], 0.f);
  }
  __syncthreads();
  // ---- layer 2 ----
  {
    float bias = b2[i];
    #pragma unroll
    for (int k = 0; k < RPT; ++k) acc[k] = bias;
    const float4* wv4 = (const float4*)(W2 + (size_t)i * H);
    for (int q = 0; q < 32; ++q) {
      float4 wv = wv4[q];
      #pragma unroll
      for (int k = 0; k < RPT; ++k) {
        float4 fv = *(const float4*)&hrow[rg * RPT + k][4 * q];
        acc[k] += wv.x * fv.x + wv.y * fv.y + wv.z * fv.z + wv.w * fv.w;
      }
    }
    #pragma unroll
    for (int k = 0; k < RPT; ++k) {
      int r = row0 + rg * RPT + k;
      if (r < N) out[(size_t)r * H + i] = acc[k];
    }
  }
}

extern "C" void kernel_launch(void* const* d_in, const int* in_sizes, int n_in,
                              void* d_out, int out_size, void* d_ws, size_t ws_size,
                              hipStream_t stream) {
  const int* src = (const int*)d_in[0];
  const int* dst = (const int*)d_in[1];
  const int* rel = (const int*)d_in[2];
  const int* inv = (const int*)d_in[3];
  const float* ent   = (const float*)d_in[4];
  const float* rhead = (const float*)d_in[5];
  const float* rtail = (const float*)d_in[6];
  const float* resent = (const float*)d_in[7];
  const float* W1 = (const float*)d_in[8];
  const float* b1 = (const float*)d_in[9];
  const float* W2 = (const float*)d_in[10];
  const float* b2 = (const float*)d_in[11];
  int E = in_sizes[0];
  int N = in_sizes[4] / H;
  int NRES_ = in_sizes[7] / H;
  float* out = (float*)d_out;

  char* ws = (char*)d_ws;
  size_t padN = (((size_t)N * 4) + 255) & ~(size_t)255;
  int* in_deg  = (int*)ws;
  int* out_deg = (int*)(ws + padN);
  int* cursor  = (int*)(ws + 2 * padN);
  int* zcount  = (int*)(ws + 3 * padN);
  size_t base = 3 * padN + 256;
  int* offs = (int*)(ws + base);  base += (((size_t)(N + 1) * 4) + 255) & ~(size_t)255;
  int* zlist = (int*)(ws + base); base += padN;
  int* bucket = (int*)(ws + base); base += (((size_t)E * 4) + 255) & ~(size_t)255;
  float* z2 = (float*)(ws + base); base += (((size_t)NRES_ * H * 4) + 255) & ~(size_t)255;
  float* feat = out;  // reuse d_out as feat storage (per-row ownership in MLP)

  // zero in_deg/out_deg/cursor/zcount in one memset (contiguous)
  hipMemsetAsync(in_deg, 0, 3 * padN + 256, stream);

  deg_kernel<<<(E + 255) / 256, 256, 0, stream>>>(src, dst, in_deg, out_deg, E);
  scan_kernel<<<1, 1024, 0, stream>>>(in_deg, offs, N);
  fill_kernel<<<(E + 255) / 256, 256, 0, stream>>>(dst, rel, inv, offs, cursor, bucket, E);
  zerolist_kernel<<<(N + 255) / 256, 256, 0, stream>>>(in_deg, out_deg, zlist, zcount, N);
  norm_res_kernel<<<NRES_, 64, 0, stream>>>(resent, z2);
  gather_kernel<<<(N + 3) / 4, 256, 0, stream>>>(offs, bucket, rhead, rtail, feat, N);
  zero_emb_kernel<<<512, 256, 0, stream>>>(zlist, zcount, ent, z2, resent, feat, NRES_);
  mlp_kernel<<<(N + ROWS - 1) / ROWS, 256, 0, stream>>>(feat, W1, b1, W2, b2, out, N);
}